// Round 3
// baseline (1859.972 us; speedup 1.0000x reference)
//
#include <hip/hip_runtime.h>

#define U_CNT 100001
#define I_CNT 50001
#define N_CNT 150002
#define DIM 64
#define SCAN_T 1024

// degree histogram (deg == row counts, matches reference segment_sum of ones)
__global__ void hist_kernel(const int* __restrict__ rows, int* __restrict__ counts,
                            int nnz) {
    int i = blockIdx.x * blockDim.x + threadIdx.x;
    if (i >= nnz) return;
    atomicAdd(&counts[rows[i]], 1);
}

// init: dinv = (counts+1e-7)^-1/2 ; hs0 = dinv .* emb ; acc = emb
__global__ void init_kernel(const float4* __restrict__ ue,
                            const float4* __restrict__ ie,
                            const int* __restrict__ counts,
                            float* __restrict__ dinv,
                            float4* __restrict__ hs,
                            float4* __restrict__ acc) {
    int i = blockIdx.x * blockDim.x + threadIdx.x;   // over N_CNT*16 float4s
    if (i >= N_CNT * 16) return;
    int node = i >> 4;
    float deg = (float)counts[node] + 1e-7f;
    float d = 1.0f / sqrtf(deg);
    if ((i & 15) == 0) dinv[node] = d;
    float4 v = (i < U_CNT * 16) ? ue[i] : ie[i - U_CNT * 16];
    acc[i] = v;
    float4 h;
    h.x = d * v.x; h.y = d * v.y; h.z = d * v.z; h.w = d * v.w;
    hs[i] = h;
}

// single-block exclusive scan of counts[N_CNT] -> row_ptr[N_CNT+1], fill = copy
__global__ void scan_kernel(const int* __restrict__ counts,
                            int* __restrict__ row_ptr,
                            int* __restrict__ fill) {
    __shared__ int lds[SCAN_T];
    const int t = threadIdx.x;
    const int CH = (N_CNT + SCAN_T - 1) / SCAN_T;
    int b = t * CH;
    int e = b + CH; if (e > N_CNT) e = N_CNT;
    int s = 0;
    for (int i = b; i < e; ++i) s += counts[i];
    lds[t] = s;
    __syncthreads();
    for (int off = 1; off < SCAN_T; off <<= 1) {
        int v = (t >= off) ? lds[t - off] : 0;
        __syncthreads();
        lds[t] += v;
        __syncthreads();
    }
    int run = (t == 0) ? 0 : lds[t - 1];
    for (int i = b; i < e; ++i) {
        int c = counts[i];
        row_ptr[i] = run;
        fill[i] = run;
        run += c;
    }
    if (t == 0) row_ptr[N_CNT] = lds[SCAN_T - 1];
}

// scatter col indices only into CSR order (no vals needed)
__global__ void scatter_kernel(const int* __restrict__ rows,
                               const int* __restrict__ cols,
                               int* __restrict__ fill,
                               int* __restrict__ col_s,
                               int nnz) {
    int i = blockIdx.x * blockDim.x + threadIdx.x;
    if (i >= nnz) return;
    int r = rows[i];
    int p = atomicAdd(&fill[r], 1);
    col_s[p] = cols[i];
}

// gather SpMM on pre-scaled hs: t[r] = sum_j hs[col[j]]
// then hs_next = dinv[r]^2 * t ; acc += dinv[r] * t (scaled by 0.25 on last)
__global__ void spmm_gather(const int* __restrict__ row_ptr,
                            const int* __restrict__ col_s,
                            const float* __restrict__ dinv,
                            const float4* __restrict__ x,
                            float4* __restrict__ y,
                            float4* __restrict__ acc,
                            int last) {
    int r = blockIdx.x * 16 + (threadIdx.x >> 4);
    int s = threadIdx.x & 15;
    if (r >= N_CNT) return;
    int beg = row_ptr[r];
    int end = row_ptr[r + 1];
    float4 a; a.x = 0.f; a.y = 0.f; a.z = 0.f; a.w = 0.f;
    float4 b; b.x = 0.f; b.y = 0.f; b.z = 0.f; b.w = 0.f;
    int j = beg;
    for (; j + 4 <= end; j += 4) {
        int c0 = col_s[j];
        int c1 = col_s[j + 1];
        int c2 = col_s[j + 2];
        int c3 = col_s[j + 3];
        float4 x0 = x[(size_t)c0 * 16 + s];
        float4 x1 = x[(size_t)c1 * 16 + s];
        float4 x2 = x[(size_t)c2 * 16 + s];
        float4 x3 = x[(size_t)c3 * 16 + s];
        a.x += x0.x; a.y += x0.y; a.z += x0.z; a.w += x0.w;
        b.x += x1.x; b.y += x1.y; b.z += x1.z; b.w += x1.w;
        a.x += x2.x; a.y += x2.y; a.z += x2.z; a.w += x2.w;
        b.x += x3.x; b.y += x3.y; b.z += x3.z; b.w += x3.w;
    }
    for (; j < end; ++j) {
        int c0 = col_s[j];
        float4 x0 = x[(size_t)c0 * 16 + s];
        a.x += x0.x; a.y += x0.y; a.z += x0.z; a.w += x0.w;
    }
    a.x += b.x; a.y += b.y; a.z += b.z; a.w += b.w;

    float d = dinv[r];
    float d2 = d * d;
    size_t o = (size_t)r * 16 + s;
    float4 hn;
    hn.x = d2 * a.x; hn.y = d2 * a.y; hn.z = d2 * a.z; hn.w = d2 * a.w;
    y[o] = hn;                                   // hs for next layer
    float4 ac = acc[o];
    ac.x += d * a.x; ac.y += d * a.y; ac.z += d * a.z; ac.w += d * a.w;
    if (last) { ac.x *= 0.25f; ac.y *= 0.25f; ac.z *= 0.25f; ac.w *= 0.25f; }
    acc[o] = ac;
}

extern "C" void kernel_launch(void* const* d_in, const int* in_sizes, int n_in,
                              void* d_out, int out_size, void* d_ws, size_t ws_size,
                              hipStream_t stream) {
    const float* ue   = (const float*)d_in[0];
    const float* ie   = (const float*)d_in[1];
    const int*   rows = (const int*)d_in[2];
    const int*   cols = (const int*)d_in[3];
    int nnz = in_sizes[2];

    float* acc = (float*)d_out;

    // workspace layout
    float* h0      = (float*)d_ws;                       // N*64 floats (hs ping)
    float* h1      = h0 + (size_t)N_CNT * DIM;           // N*64 floats (hs pong)
    int*   counts  = (int*)(h1 + (size_t)N_CNT * DIM);   // N
    int*   row_ptr = counts + N_CNT;                     // N+1
    int*   fill    = row_ptr + (N_CNT + 1);              // N
    float* dinv    = (float*)(fill + N_CNT);             // N
    int*   col_s   = (int*)(dinv + N_CNT);               // nnz

    const int nvec = N_CNT * 16;
    const int tpb  = 256;

    // ---- degrees ----
    hipMemsetAsync(counts, 0, (size_t)N_CNT * sizeof(int), stream);
    hist_kernel<<<(nnz + tpb - 1) / tpb, tpb, 0, stream>>>(rows, counts, nnz);

    // ---- dinv + initial embeddings (pre-scaled) ----
    init_kernel<<<(nvec + tpb - 1) / tpb, tpb, 0, stream>>>(
        (const float4*)ue, (const float4*)ie, counts, dinv,
        (float4*)h0, (float4*)acc);

    // ---- CSR build ----
    scan_kernel<<<1, SCAN_T, 0, stream>>>(counts, row_ptr, fill);
    scatter_kernel<<<(nnz + tpb - 1) / tpb, tpb, 0, stream>>>(
        rows, cols, fill, col_s, nnz);

    // ---- 3 propagation layers, acc fused ----
    float* cur = h0;
    float* nxt = h1;
    const int rows_per_block = tpb / 16;                 // 16
    const int gblocks = (N_CNT + rows_per_block - 1) / rows_per_block;
    for (int l = 0; l < 3; ++l) {
        spmm_gather<<<gblocks, tpb, 0, stream>>>(
            row_ptr, col_s, dinv, (const float4*)cur,
            (float4*)nxt, (float4*)acc, l == 2 ? 1 : 0);
        float* tmp = cur; cur = nxt; nxt = tmp;
    }
}

// Round 4
// 1378.960 us; speedup vs baseline: 1.3488x; 1.3488x over previous
//
#include <hip/hip_runtime.h>
#include <hip/hip_fp16.h>

#define U_CNT 100001
#define I_CNT 50001
#define N_CNT 150002
#define DIM 64
#define SCAN_T 1024
#define NB ((N_CNT + 15) / 16)   // 9376 buckets of 16 rows

__device__ inline __half2 u2h(unsigned int u) { union { unsigned int u; __half2 h; } c; c.u = u; return c.h; }
__device__ inline unsigned int h2u(__half2 h) { union { unsigned int u; __half2 h; } c; c.h = h; return c.u; }

// degree histogram
__global__ void hist_kernel(const int* __restrict__ rows, int* __restrict__ counts,
                            int nnz) {
    int i = blockIdx.x * blockDim.x + threadIdx.x;
    if (i >= nnz) return;
    atomicAdd(&counts[rows[i]], 1);
}

// init: dinv = (counts+1e-7)^-1/2 ; hs0 = fp16(dinv .* emb) ; acc = emb (f32)
// one thread per 8 consecutive floats of a row (N*8 threads)
__global__ void init_kernel(const float4* __restrict__ ue,
                            const float4* __restrict__ ie,
                            const int* __restrict__ counts,
                            float* __restrict__ dinv,
                            uint4* __restrict__ hs,
                            float4* __restrict__ acc) {
    int i = blockIdx.x * blockDim.x + threadIdx.x;   // over N_CNT*8
    if (i >= N_CNT * 8) return;
    int node = i >> 3;
    int s = i & 7;
    float deg = (float)counts[node] + 1e-7f;
    float d = 1.0f / sqrtf(deg);
    if (s == 0) dinv[node] = d;
    size_t fo = (size_t)node * 16 + s * 2;
    float4 v0, v1;
    if (node < U_CNT) { v0 = ue[fo]; v1 = ue[fo + 1]; }
    else { size_t io = fo - (size_t)U_CNT * 16; v0 = ie[io]; v1 = ie[io + 1]; }
    acc[fo] = v0;
    acc[fo + 1] = v1;
    uint4 h;
    h.x = h2u(__floats2half2_rn(d * v0.x, d * v0.y));
    h.y = h2u(__floats2half2_rn(d * v0.z, d * v0.w));
    h.z = h2u(__floats2half2_rn(d * v1.x, d * v1.y));
    h.w = h2u(__floats2half2_rn(d * v1.z, d * v1.w));
    hs[(size_t)node * 8 + s] = h;
}

// single-block exclusive scan of counts -> row_ptr[N+1]; also bucket cursors
__global__ void scan_kernel(const int* __restrict__ counts,
                            int* __restrict__ row_ptr,
                            int* __restrict__ bcur) {
    __shared__ int lds[SCAN_T];
    const int t = threadIdx.x;
    const int CH = (N_CNT + SCAN_T - 1) / SCAN_T;
    int b = t * CH;
    int e = b + CH; if (e > N_CNT) e = N_CNT;
    int s = 0;
    for (int i = b; i < e; ++i) s += counts[i];
    lds[t] = s;
    __syncthreads();
    for (int off = 1; off < SCAN_T; off <<= 1) {
        int v = (t >= off) ? lds[t - off] : 0;
        __syncthreads();
        lds[t] += v;
        __syncthreads();
    }
    int run = (t == 0) ? 0 : lds[t - 1];
    for (int i = b; i < e; ++i) {
        int c = counts[i];
        row_ptr[i] = run;
        if ((i & 15) == 0) bcur[i >> 4] = run;
        run += c;
    }
    if (t == 0) row_ptr[N_CNT] = lds[SCAN_T - 1];
}

// phase A: bin edges by row>>4 into staging; record packs (col<<4)|row_low
__global__ void bucket_kernel(const int* __restrict__ rows,
                              const int* __restrict__ cols,
                              int* __restrict__ bcur,
                              unsigned int* __restrict__ staging,
                              int nnz) {
    int i = blockIdx.x * blockDim.x + threadIdx.x;
    if (i >= nnz) return;
    int r = rows[i];
    int c = cols[i];
    int p = atomicAdd(&bcur[r >> 4], 1);
    staging[p] = ((unsigned int)c << 4) | (unsigned int)(r & 15);
}

// phase B: one block per bucket; place cols into final CSR order within the
// bucket's contiguous window using 16 LDS cursors
__global__ void binplace_kernel(const int* __restrict__ row_ptr,
                                const unsigned int* __restrict__ staging,
                                unsigned int* __restrict__ col_s) {
    __shared__ int cur[16];
    int b = blockIdx.x;
    int base = b << 4;
    if (threadIdx.x < 16) {
        int r = base + threadIdx.x;
        cur[threadIdx.x] = (r < N_CNT) ? row_ptr[r] : 0;
    }
    __syncthreads();
    int beg = row_ptr[base];
    int top = base + 16; if (top > N_CNT) top = N_CNT;
    int end = row_ptr[top];
    for (int j = beg + threadIdx.x; j < end; j += blockDim.x) {
        unsigned int rec = staging[j];
        int pos = atomicAdd(&cur[rec & 15u], 1);
        col_s[pos] = rec >> 4;
    }
}

__device__ inline void acc8(float4& a0, float4& a1, uint4 u) {
    float2 f;
    f = __half22float2(u2h(u.x)); a0.x += f.x; a0.y += f.y;
    f = __half22float2(u2h(u.y)); a0.z += f.x; a0.w += f.y;
    f = __half22float2(u2h(u.z)); a1.x += f.x; a1.y += f.y;
    f = __half22float2(u2h(u.w)); a1.z += f.x; a1.w += f.y;
}

// gather SpMM on fp16 pre-scaled hs: 8 lanes per row, 16B per lane.
// t[r] = sum_j hs[col[j]]; hs_next = fp16(d^2 * t); acc += d * t (x0.25 last)
__global__ void spmm_gather(const int* __restrict__ row_ptr,
                            const unsigned int* __restrict__ col_s,
                            const float* __restrict__ dinv,
                            const uint4* __restrict__ x,
                            uint4* __restrict__ y,
                            float4* __restrict__ acc,
                            int last) {
    int r = blockIdx.x * 32 + (threadIdx.x >> 3);
    int s = threadIdx.x & 7;
    if (r >= N_CNT) return;
    int beg = row_ptr[r];
    int end = row_ptr[r + 1];
    float4 a0 = {0.f, 0.f, 0.f, 0.f}, a1 = {0.f, 0.f, 0.f, 0.f};
    float4 b0 = {0.f, 0.f, 0.f, 0.f}, b1 = {0.f, 0.f, 0.f, 0.f};
    int j = beg;
    for (; j + 4 <= end; j += 4) {
        unsigned int c0 = col_s[j];
        unsigned int c1 = col_s[j + 1];
        unsigned int c2 = col_s[j + 2];
        unsigned int c3 = col_s[j + 3];
        uint4 u0 = x[(size_t)c0 * 8 + s];
        uint4 u1 = x[(size_t)c1 * 8 + s];
        uint4 u2 = x[(size_t)c2 * 8 + s];
        uint4 u3 = x[(size_t)c3 * 8 + s];
        acc8(a0, a1, u0);
        acc8(b0, b1, u1);
        acc8(a0, a1, u2);
        acc8(b0, b1, u3);
    }
    for (; j < end; ++j) {
        unsigned int c0 = col_s[j];
        uint4 u0 = x[(size_t)c0 * 8 + s];
        acc8(a0, a1, u0);
    }
    a0.x += b0.x; a0.y += b0.y; a0.z += b0.z; a0.w += b0.w;
    a1.x += b1.x; a1.y += b1.y; a1.z += b1.z; a1.w += b1.w;

    float d = dinv[r];
    float d2 = d * d;
    uint4 h;
    h.x = h2u(__floats2half2_rn(d2 * a0.x, d2 * a0.y));
    h.y = h2u(__floats2half2_rn(d2 * a0.z, d2 * a0.w));
    h.z = h2u(__floats2half2_rn(d2 * a1.x, d2 * a1.y));
    h.w = h2u(__floats2half2_rn(d2 * a1.z, d2 * a1.w));
    y[(size_t)r * 8 + s] = h;

    size_t o = (size_t)r * 16 + s * 2;
    float4 c0 = acc[o];
    float4 c1 = acc[o + 1];
    c0.x += d * a0.x; c0.y += d * a0.y; c0.z += d * a0.z; c0.w += d * a0.w;
    c1.x += d * a1.x; c1.y += d * a1.y; c1.z += d * a1.z; c1.w += d * a1.w;
    if (last) {
        c0.x *= 0.25f; c0.y *= 0.25f; c0.z *= 0.25f; c0.w *= 0.25f;
        c1.x *= 0.25f; c1.y *= 0.25f; c1.z *= 0.25f; c1.w *= 0.25f;
    }
    acc[o] = c0;
    acc[o + 1] = c1;
}

extern "C" void kernel_launch(void* const* d_in, const int* in_sizes, int n_in,
                              void* d_out, int out_size, void* d_ws, size_t ws_size,
                              hipStream_t stream) {
    const float* ue   = (const float*)d_in[0];
    const float* ie   = (const float*)d_in[1];
    const int*   rows = (const int*)d_in[2];
    const int*   cols = (const int*)d_in[3];
    int nnz = in_sizes[2];

    float* acc = (float*)d_out;

    // workspace layout (hs buffers first for 16B alignment)
    unsigned int* ws = (unsigned int*)d_ws;
    uint4* hs0 = (uint4*)ws;                               // N*8 uint4 (fp16 hs)
    uint4* hs1 = hs0 + (size_t)N_CNT * 8;                  // N*8 uint4
    int*   counts  = (int*)(hs1 + (size_t)N_CNT * 8);      // N
    int*   row_ptr = counts + N_CNT;                       // N+1
    int*   bcur    = row_ptr + (N_CNT + 1);                // NB
    float* dinv    = (float*)(bcur + NB);                  // N
    unsigned int* staging = (unsigned int*)(dinv + N_CNT); // nnz
    unsigned int* col_s   = staging + nnz;                 // nnz

    const int tpb = 256;

    // ---- degrees ----
    hipMemsetAsync(counts, 0, (size_t)N_CNT * sizeof(int), stream);
    hist_kernel<<<(nnz + tpb - 1) / tpb, tpb, 0, stream>>>(rows, counts, nnz);

    // ---- dinv + initial embeddings ----
    init_kernel<<<(N_CNT * 8 + tpb - 1) / tpb, tpb, 0, stream>>>(
        (const float4*)ue, (const float4*)ie, counts, dinv, hs0, (float4*)acc);

    // ---- CSR build: scan, bucket scatter, local place ----
    scan_kernel<<<1, SCAN_T, 0, stream>>>(counts, row_ptr, bcur);
    bucket_kernel<<<(nnz + tpb - 1) / tpb, tpb, 0, stream>>>(
        rows, cols, bcur, staging, nnz);
    binplace_kernel<<<NB, tpb, 0, stream>>>(row_ptr, staging, col_s);

    // ---- 3 propagation layers, acc fused ----
    uint4* cur = hs0;
    uint4* nxt = hs1;
    const int gblocks = (N_CNT + 31) / 32;
    for (int l = 0; l < 3; ++l) {
        spmm_gather<<<gblocks, tpb, 0, stream>>>(
            row_ptr, col_s, dinv, cur, nxt, (float4*)acc, l == 2 ? 1 : 0);
        uint4* tmp = cur; cur = nxt; nxt = tmp;
    }
}

// Round 5
// 1081.640 us; speedup vs baseline: 1.7196x; 1.2749x over previous
//
#include <hip/hip_runtime.h>
#include <hip/hip_fp16.h>

#define U_CNT 100001
#define I_CNT 50001
#define N_CNT 150002
#define DIM 64
#define SCAN_T 1024
#define BROWS 512                       // rows per bucket
#define NB2 ((N_CNT + BROWS - 1) / BROWS)   // 293 buckets
#define NB2P 512                        // padded for block scan
#define CH 8192                         // edges per partition block

__device__ inline __half2 u2h(unsigned int u) { union { unsigned int u; __half2 h; } c; c.u = u; return c.h; }
__device__ inline unsigned int h2u(__half2 h) { union { unsigned int u; __half2 h; } c; c.h = h; return c.u; }

// degree histogram
__global__ void hist_kernel(const int* __restrict__ rows, int* __restrict__ counts,
                            int nnz) {
    int i = blockIdx.x * blockDim.x + threadIdx.x;
    if (i >= nnz) return;
    atomicAdd(&counts[rows[i]], 1);
}

// init: dinv = (counts+1e-7)^-1/2 ; hs0 = fp16(dinv .* emb) ; acc = emb (f32)
__global__ void init_kernel(const float4* __restrict__ ue,
                            const float4* __restrict__ ie,
                            const int* __restrict__ counts,
                            float* __restrict__ dinv,
                            uint4* __restrict__ hs,
                            float4* __restrict__ acc) {
    int i = blockIdx.x * blockDim.x + threadIdx.x;   // over N_CNT*8
    if (i >= N_CNT * 8) return;
    int node = i >> 3;
    int s = i & 7;
    float deg = (float)counts[node] + 1e-7f;
    float d = 1.0f / sqrtf(deg);
    if (s == 0) dinv[node] = d;
    size_t fo = (size_t)node * 16 + s * 2;
    float4 v0, v1;
    if (node < U_CNT) { v0 = ue[fo]; v1 = ue[fo + 1]; }
    else { size_t io = fo - (size_t)U_CNT * 16; v0 = ie[io]; v1 = ie[io + 1]; }
    acc[fo] = v0;
    acc[fo + 1] = v1;
    uint4 h;
    h.x = h2u(__floats2half2_rn(d * v0.x, d * v0.y));
    h.y = h2u(__floats2half2_rn(d * v0.z, d * v0.w));
    h.z = h2u(__floats2half2_rn(d * v1.x, d * v1.y));
    h.w = h2u(__floats2half2_rn(d * v1.z, d * v1.w));
    hs[(size_t)node * 8 + s] = h;
}

// single-block exclusive scan of counts -> row_ptr[N+1]; bucket cursors per 512 rows
__global__ void scan_kernel(const int* __restrict__ counts,
                            int* __restrict__ row_ptr,
                            int* __restrict__ bcur) {
    __shared__ int lds[SCAN_T];
    const int t = threadIdx.x;
    const int CHN = (N_CNT + SCAN_T - 1) / SCAN_T;
    int b = t * CHN;
    int e = b + CHN; if (e > N_CNT) e = N_CNT;
    int s = 0;
    for (int i = b; i < e; ++i) s += counts[i];
    lds[t] = s;
    __syncthreads();
    for (int off = 1; off < SCAN_T; off <<= 1) {
        int v = (t >= off) ? lds[t - off] : 0;
        __syncthreads();
        lds[t] += v;
        __syncthreads();
    }
    int run = (t == 0) ? 0 : lds[t - 1];
    for (int i = b; i < e; ++i) {
        int c = counts[i];
        row_ptr[i] = run;
        if ((i & (BROWS - 1)) == 0) bcur[i / BROWS] = run;
        run += c;
    }
    if (t == 0) row_ptr[N_CNT] = lds[SCAN_T - 1];
}

// phase A: block-local counting sort of an 8192-edge chunk into 293 buckets,
// then contiguous run-writes to global staging. Record = (col<<9)|(row&511).
__global__ void __launch_bounds__(256) partition_kernel(
    const int* __restrict__ rows, const int* __restrict__ cols,
    int* __restrict__ bcur, unsigned int* __restrict__ staging, int nnz)
{
    __shared__ int hist[NB2P];
    __shared__ int ofs[NB2 + 1];
    __shared__ int cur[NB2];
    __shared__ int gbase[NB2];
    __shared__ unsigned int recs[CH];
    const int t = threadIdx.x;
    int base = blockIdx.x * CH;
    int lim = nnz - base; if (lim > CH) lim = CH;

    for (int i = t; i < NB2P; i += 256) hist[i] = 0;
    __syncthreads();
    // 1: histogram
    for (int i = t; i < lim; i += 256)
        atomicAdd(&hist[rows[base + i] >> 9], 1);
    __syncthreads();
    // 2: Hillis-Steele inclusive scan over 512 entries (2 per thread)
    for (int off = 1; off < NB2P; off <<= 1) {
        int v0 = (t >= off) ? hist[t - off] : 0;
        int i1 = t + 256;
        int v1 = hist[i1 - off];
        __syncthreads();
        hist[t] += v0;
        hist[i1] += v1;
        __syncthreads();
    }
    for (int i = t; i <= NB2; i += 256)
        ofs[i] = (i == 0) ? 0 : hist[i - 1];
    __syncthreads();
    for (int i = t; i < NB2; i += 256)
        cur[i] = ofs[i];
    __syncthreads();
    // 3: reserve global space per bucket
    for (int i = t; i < NB2; i += 256) {
        int cnt = ofs[i + 1] - ofs[i];
        if (cnt) gbase[i] = atomicAdd(&bcur[i], cnt);
    }
    // 4: local scatter into recs at scanned positions
    for (int i = t; i < lim; i += 256) {
        int r = rows[base + i];
        int c = cols[base + i];
        int p = atomicAdd(&cur[r >> 9], 1);
        recs[p] = ((unsigned int)c << 9) | (unsigned int)(r & (BROWS - 1));
    }
    __syncthreads();
    // 5: coalesced run-writes; bucket of position p via binary search in ofs
    for (int p = t; p < lim; p += 256) {
        unsigned int rec = recs[p];
        int lo = 0, hi = NB2;
        while (hi - lo > 1) {
            int mid = (lo + hi) >> 1;
            if (ofs[mid] <= p) lo = mid; else hi = mid;
        }
        staging[gbase[lo] + (p - ofs[lo])] = rec;
    }
}

// phase B: one block per 512-row bucket; place cols into final CSR order
__global__ void binplace_kernel(const int* __restrict__ row_ptr,
                                const unsigned int* __restrict__ staging,
                                unsigned int* __restrict__ col_s) {
    __shared__ int cur[BROWS];
    int base = blockIdx.x << 9;
    int top = base + BROWS; if (top > N_CNT) top = N_CNT;
    for (int i = threadIdx.x; i < top - base; i += blockDim.x)
        cur[i] = row_ptr[base + i];
    __syncthreads();
    int beg = row_ptr[base];
    int end = row_ptr[top];
    for (int j = beg + threadIdx.x; j < end; j += blockDim.x) {
        unsigned int rec = staging[j];
        int pos = atomicAdd(&cur[rec & (BROWS - 1u)], 1);
        col_s[pos] = rec >> 9;
    }
}

__device__ inline void acc8(float4& a0, float4& a1, uint4 u) {
    float2 f;
    f = __half22float2(u2h(u.x)); a0.x += f.x; a0.y += f.y;
    f = __half22float2(u2h(u.y)); a0.z += f.x; a0.w += f.y;
    f = __half22float2(u2h(u.z)); a1.x += f.x; a1.y += f.y;
    f = __half22float2(u2h(u.w)); a1.z += f.x; a1.w += f.y;
}

// gather SpMM on fp16 pre-scaled hs over row range [r0, r1)
__global__ void spmm_gather(const int* __restrict__ row_ptr,
                            const unsigned int* __restrict__ col_s,
                            const float* __restrict__ dinv,
                            const uint4* __restrict__ x,
                            uint4* __restrict__ y,
                            float4* __restrict__ acc,
                            int r0, int r1, int last) {
    int r = r0 + blockIdx.x * 32 + (threadIdx.x >> 3);
    int s = threadIdx.x & 7;
    if (r >= r1) return;
    int beg = row_ptr[r];
    int end = row_ptr[r + 1];
    float4 a0 = {0.f, 0.f, 0.f, 0.f}, a1 = {0.f, 0.f, 0.f, 0.f};
    float4 b0 = {0.f, 0.f, 0.f, 0.f}, b1 = {0.f, 0.f, 0.f, 0.f};
    int j = beg;
    for (; j + 4 <= end; j += 4) {
        unsigned int c0 = col_s[j];
        unsigned int c1 = col_s[j + 1];
        unsigned int c2 = col_s[j + 2];
        unsigned int c3 = col_s[j + 3];
        uint4 u0 = x[(size_t)c0 * 8 + s];
        uint4 u1 = x[(size_t)c1 * 8 + s];
        uint4 u2 = x[(size_t)c2 * 8 + s];
        uint4 u3 = x[(size_t)c3 * 8 + s];
        acc8(a0, a1, u0);
        acc8(b0, b1, u1);
        acc8(a0, a1, u2);
        acc8(b0, b1, u3);
    }
    for (; j < end; ++j) {
        unsigned int c0 = col_s[j];
        uint4 u0 = x[(size_t)c0 * 8 + s];
        acc8(a0, a1, u0);
    }
    a0.x += b0.x; a0.y += b0.y; a0.z += b0.z; a0.w += b0.w;
    a1.x += b1.x; a1.y += b1.y; a1.z += b1.z; a1.w += b1.w;

    float d = dinv[r];
    float d2 = d * d;
    uint4 h;
    h.x = h2u(__floats2half2_rn(d2 * a0.x, d2 * a0.y));
    h.y = h2u(__floats2half2_rn(d2 * a0.z, d2 * a0.w));
    h.z = h2u(__floats2half2_rn(d2 * a1.x, d2 * a1.y));
    h.w = h2u(__floats2half2_rn(d2 * a1.z, d2 * a1.w));
    y[(size_t)r * 8 + s] = h;

    size_t o = (size_t)r * 16 + s * 2;
    float4 c0 = acc[o];
    float4 c1 = acc[o + 1];
    c0.x += d * a0.x; c0.y += d * a0.y; c0.z += d * a0.z; c0.w += d * a0.w;
    c1.x += d * a1.x; c1.y += d * a1.y; c1.z += d * a1.z; c1.w += d * a1.w;
    if (last) {
        c0.x *= 0.25f; c0.y *= 0.25f; c0.z *= 0.25f; c0.w *= 0.25f;
        c1.x *= 0.25f; c1.y *= 0.25f; c1.z *= 0.25f; c1.w *= 0.25f;
    }
    acc[o] = c0;
    acc[o + 1] = c1;
}

extern "C" void kernel_launch(void* const* d_in, const int* in_sizes, int n_in,
                              void* d_out, int out_size, void* d_ws, size_t ws_size,
                              hipStream_t stream) {
    const float* ue   = (const float*)d_in[0];
    const float* ie   = (const float*)d_in[1];
    const int*   rows = (const int*)d_in[2];
    const int*   cols = (const int*)d_in[3];
    int nnz = in_sizes[2];

    float* acc = (float*)d_out;

    unsigned int* ws = (unsigned int*)d_ws;
    uint4* hs0 = (uint4*)ws;                               // N*8 uint4 (fp16 hs)
    uint4* hs1 = hs0 + (size_t)N_CNT * 8;                  // N*8 uint4
    int*   counts  = (int*)(hs1 + (size_t)N_CNT * 8);      // N
    int*   row_ptr = counts + N_CNT;                       // N+1
    int*   bcur    = row_ptr + (N_CNT + 1);                // NB2
    float* dinv    = (float*)(bcur + NB2);                 // N
    unsigned int* staging = (unsigned int*)(dinv + N_CNT); // nnz
    unsigned int* col_s   = staging + nnz;                 // nnz

    const int tpb = 256;

    // ---- degrees ----
    hipMemsetAsync(counts, 0, (size_t)N_CNT * sizeof(int), stream);
    hist_kernel<<<(nnz + tpb - 1) / tpb, tpb, 0, stream>>>(rows, counts, nnz);

    // ---- dinv + initial embeddings ----
    init_kernel<<<(N_CNT * 8 + tpb - 1) / tpb, tpb, 0, stream>>>(
        (const float4*)ue, (const float4*)ie, counts, dinv, hs0, (float4*)acc);

    // ---- CSR build: scan, block-local counting-sort partition, local place ----
    scan_kernel<<<1, SCAN_T, 0, stream>>>(counts, row_ptr, bcur);
    partition_kernel<<<(nnz + CH - 1) / CH, tpb, 0, stream>>>(
        rows, cols, bcur, staging, nnz);
    binplace_kernel<<<NB2, 512, 0, stream>>>(row_ptr, staging, col_s);

    // ---- 3 propagation layers, split user/item for L2 locality ----
    uint4* cur = hs0;
    uint4* nxt = hs1;
    const int ublocks = (U_CNT + 31) / 32;
    const int iblocks = (N_CNT - U_CNT + 31) / 32;
    for (int l = 0; l < 3; ++l) {
        int last = (l == 2) ? 1 : 0;
        spmm_gather<<<ublocks, tpb, 0, stream>>>(
            row_ptr, col_s, dinv, cur, nxt, (float4*)acc, 0, U_CNT, last);
        spmm_gather<<<iblocks, tpb, 0, stream>>>(
            row_ptr, col_s, dinv, cur, nxt, (float4*)acc, U_CNT, N_CNT, last);
        uint4* tmp = cur; cur = nxt; nxt = tmp;
    }
}

// Round 6
// 633.443 us; speedup vs baseline: 2.9363x; 1.7076x over previous
//
#include <hip/hip_runtime.h>
#include <hip/hip_fp16.h>

#define U_CNT 100001
#define I_CNT 50001
#define N_CNT 150002
#define DIM 64
#define BROWS 512                           // rows per bucket
#define NB2 ((N_CNT + BROWS - 1) / BROWS)   // 293 buckets
#define NB2P 512                            // padded for block scan
#define CH 8192                             // edges per partition block

__device__ inline __half2 u2h(unsigned int u) { union { unsigned int u; __half2 h; } c; c.u = u; return c.h; }
__device__ inline unsigned int h2u(__half2 h) { union { unsigned int u; __half2 h; } c; c.h = h; return c.u; }

// LDS-privatized bucket histogram (293 bins) — no per-row global atomics
__global__ void bucket_hist(const int* __restrict__ rows, int* __restrict__ bhist,
                            int nnz) {
    __shared__ int lh[NB2];
    for (int i = threadIdx.x; i < NB2; i += blockDim.x) lh[i] = 0;
    __syncthreads();
    int stride = gridDim.x * blockDim.x;
    for (int i = blockIdx.x * blockDim.x + threadIdx.x; i < nnz; i += stride)
        atomicAdd(&lh[rows[i] >> 9], 1);
    __syncthreads();
    for (int i = threadIdx.x; i < NB2; i += blockDim.x) {
        int v = lh[i];
        if (v) atomicAdd(&bhist[i], v);
    }
}

// trivial serial scan of 293 bucket totals -> bucket_ptr[294], bcur init
__global__ void bucket_scan(const int* __restrict__ bhist,
                            int* __restrict__ bucket_ptr,
                            int* __restrict__ bcur) {
    if (threadIdx.x == 0 && blockIdx.x == 0) {
        int run = 0;
        for (int i = 0; i < NB2; ++i) {
            bucket_ptr[i] = run;
            bcur[i] = run;
            run += bhist[i];
        }
        bucket_ptr[NB2] = run;
    }
}

// phase A: block-local counting sort of an 8192-edge chunk into 293 buckets,
// then contiguous run-writes to global staging. Record = (col<<9)|(row&511).
__global__ void __launch_bounds__(256) partition_kernel(
    const int* __restrict__ rows, const int* __restrict__ cols,
    int* __restrict__ bcur, unsigned int* __restrict__ staging, int nnz)
{
    __shared__ int hist[NB2P];
    __shared__ int ofs[NB2 + 1];
    __shared__ int cur[NB2];
    __shared__ int gbase[NB2];
    __shared__ unsigned int recs[CH];
    const int t = threadIdx.x;
    int base = blockIdx.x * CH;
    int lim = nnz - base; if (lim > CH) lim = CH;

    for (int i = t; i < NB2P; i += 256) hist[i] = 0;
    __syncthreads();
    for (int i = t; i < lim; i += 256)
        atomicAdd(&hist[rows[base + i] >> 9], 1);
    __syncthreads();
    for (int off = 1; off < NB2P; off <<= 1) {
        int v0 = (t >= off) ? hist[t - off] : 0;
        int i1 = t + 256;
        int v1 = hist[i1 - off];
        __syncthreads();
        hist[t] += v0;
        hist[i1] += v1;
        __syncthreads();
    }
    for (int i = t; i <= NB2; i += 256)
        ofs[i] = (i == 0) ? 0 : hist[i - 1];
    __syncthreads();
    for (int i = t; i < NB2; i += 256)
        cur[i] = ofs[i];
    __syncthreads();
    for (int i = t; i < NB2; i += 256) {
        int cnt = ofs[i + 1] - ofs[i];
        if (cnt) gbase[i] = atomicAdd(&bcur[i], cnt);
    }
    for (int i = t; i < lim; i += 256) {
        int r = rows[base + i];
        int c = cols[base + i];
        int p = atomicAdd(&cur[r >> 9], 1);
        recs[p] = ((unsigned int)c << 9) | (unsigned int)(r & (BROWS - 1));
    }
    __syncthreads();
    for (int p = t; p < lim; p += 256) {
        unsigned int rec = recs[p];
        int lo = 0, hi = NB2;
        while (hi - lo > 1) {
            int mid = (lo + hi) >> 1;
            if (ofs[mid] <= p) lo = mid; else hi = mid;
        }
        staging[gbase[lo] + (p - ofs[lo])] = rec;
    }
}

// phase B: one block per 512-row bucket. Computes per-row degrees (LDS hist),
// LDS scan -> row_ptr + dinv + cursors, then places cols into CSR order.
__global__ void binplace_kernel(const int* __restrict__ bucket_ptr,
                                const unsigned int* __restrict__ staging,
                                unsigned int* __restrict__ col_s,
                                int* __restrict__ row_ptr,
                                float* __restrict__ dinv) {
    __shared__ int hist[BROWS];
    __shared__ int cur[BROWS];
    int b = blockIdx.x;
    int base = b << 9;
    int beg = bucket_ptr[b];
    int end = bucket_ptr[b + 1];
    int t = threadIdx.x;
    hist[t] = 0;
    __syncthreads();
    for (int j = beg + t; j < end; j += BROWS)
        atomicAdd(&hist[staging[j] & (BROWS - 1u)], 1);
    __syncthreads();
    int cnt = hist[t];
    for (int off = 1; off < BROWS; off <<= 1) {
        int v = (t >= off) ? hist[t - off] : 0;
        __syncthreads();
        hist[t] += v;
        __syncthreads();
    }
    int start = beg + hist[t] - cnt;      // exclusive
    cur[t] = start;
    int r = base + t;
    if (r < N_CNT) {
        row_ptr[r] = start;
        dinv[r] = 1.0f / sqrtf((float)cnt + 1e-7f);
    }
    if (b == NB2 - 1 && t == 0) row_ptr[N_CNT] = end;
    __syncthreads();
    for (int j = beg + t; j < end; j += BROWS) {
        unsigned int rec = staging[j];
        int pos = atomicAdd(&cur[rec & (BROWS - 1u)], 1);
        col_s[pos] = rec >> 9;
    }
}

// init: hs0 = fp16(dinv .* emb) ; acc = emb (f32)
__global__ void init_kernel(const float4* __restrict__ ue,
                            const float4* __restrict__ ie,
                            const float* __restrict__ dinv,
                            uint4* __restrict__ hs,
                            float4* __restrict__ acc) {
    int i = blockIdx.x * blockDim.x + threadIdx.x;   // over N_CNT*8
    if (i >= N_CNT * 8) return;
    int node = i >> 3;
    int s = i & 7;
    float d = dinv[node];
    size_t fo = (size_t)node * 16 + s * 2;
    float4 v0, v1;
    if (node < U_CNT) { v0 = ue[fo]; v1 = ue[fo + 1]; }
    else { size_t io = fo - (size_t)U_CNT * 16; v0 = ie[io]; v1 = ie[io + 1]; }
    acc[fo] = v0;
    acc[fo + 1] = v1;
    uint4 h;
    h.x = h2u(__floats2half2_rn(d * v0.x, d * v0.y));
    h.y = h2u(__floats2half2_rn(d * v0.z, d * v0.w));
    h.z = h2u(__floats2half2_rn(d * v1.x, d * v1.y));
    h.w = h2u(__floats2half2_rn(d * v1.z, d * v1.w));
    hs[(size_t)node * 8 + s] = h;
}

__device__ inline void acc8(float4& a0, float4& a1, uint4 u) {
    float2 f;
    f = __half22float2(u2h(u.x)); a0.x += f.x; a0.y += f.y;
    f = __half22float2(u2h(u.y)); a0.z += f.x; a0.w += f.y;
    f = __half22float2(u2h(u.z)); a1.x += f.x; a1.y += f.y;
    f = __half22float2(u2h(u.w)); a1.z += f.x; a1.w += f.y;
}

// gather SpMM on fp16 pre-scaled hs over row range [r0, r1)
__global__ void spmm_gather(const int* __restrict__ row_ptr,
                            const unsigned int* __restrict__ col_s,
                            const float* __restrict__ dinv,
                            const uint4* __restrict__ x,
                            uint4* __restrict__ y,
                            float4* __restrict__ acc,
                            int r0, int r1, int last) {
    int r = r0 + blockIdx.x * 32 + (threadIdx.x >> 3);
    int s = threadIdx.x & 7;
    if (r >= r1) return;
    int beg = row_ptr[r];
    int end = row_ptr[r + 1];
    float4 a0 = {0.f, 0.f, 0.f, 0.f}, a1 = {0.f, 0.f, 0.f, 0.f};
    float4 b0 = {0.f, 0.f, 0.f, 0.f}, b1 = {0.f, 0.f, 0.f, 0.f};
    int j = beg;
    for (; j + 4 <= end; j += 4) {
        unsigned int c0 = col_s[j];
        unsigned int c1 = col_s[j + 1];
        unsigned int c2 = col_s[j + 2];
        unsigned int c3 = col_s[j + 3];
        uint4 u0 = x[(size_t)c0 * 8 + s];
        uint4 u1 = x[(size_t)c1 * 8 + s];
        uint4 u2 = x[(size_t)c2 * 8 + s];
        uint4 u3 = x[(size_t)c3 * 8 + s];
        acc8(a0, a1, u0);
        acc8(b0, b1, u1);
        acc8(a0, a1, u2);
        acc8(b0, b1, u3);
    }
    for (; j < end; ++j) {
        unsigned int c0 = col_s[j];
        uint4 u0 = x[(size_t)c0 * 8 + s];
        acc8(a0, a1, u0);
    }
    a0.x += b0.x; a0.y += b0.y; a0.z += b0.z; a0.w += b0.w;
    a1.x += b1.x; a1.y += b1.y; a1.z += b1.z; a1.w += b1.w;

    float d = dinv[r];
    float d2 = d * d;
    uint4 h;
    h.x = h2u(__floats2half2_rn(d2 * a0.x, d2 * a0.y));
    h.y = h2u(__floats2half2_rn(d2 * a0.z, d2 * a0.w));
    h.z = h2u(__floats2half2_rn(d2 * a1.x, d2 * a1.y));
    h.w = h2u(__floats2half2_rn(d2 * a1.z, d2 * a1.w));
    y[(size_t)r * 8 + s] = h;

    size_t o = (size_t)r * 16 + s * 2;
    float4 c0 = acc[o];
    float4 c1 = acc[o + 1];
    c0.x += d * a0.x; c0.y += d * a0.y; c0.z += d * a0.z; c0.w += d * a0.w;
    c1.x += d * a1.x; c1.y += d * a1.y; c1.z += d * a1.z; c1.w += d * a1.w;
    if (last) {
        c0.x *= 0.25f; c0.y *= 0.25f; c0.z *= 0.25f; c0.w *= 0.25f;
        c1.x *= 0.25f; c1.y *= 0.25f; c1.z *= 0.25f; c1.w *= 0.25f;
    }
    acc[o] = c0;
    acc[o + 1] = c1;
}

extern "C" void kernel_launch(void* const* d_in, const int* in_sizes, int n_in,
                              void* d_out, int out_size, void* d_ws, size_t ws_size,
                              hipStream_t stream) {
    const float* ue   = (const float*)d_in[0];
    const float* ie   = (const float*)d_in[1];
    const int*   rows = (const int*)d_in[2];
    const int*   cols = (const int*)d_in[3];
    int nnz = in_sizes[2];

    float* acc = (float*)d_out;

    unsigned int* ws = (unsigned int*)d_ws;
    uint4* hs0 = (uint4*)ws;                               // N*8 uint4 (fp16 hs)
    uint4* hs1 = hs0 + (size_t)N_CNT * 8;                  // N*8 uint4
    int*   row_ptr    = (int*)(hs1 + (size_t)N_CNT * 8);   // N+1
    int*   bhist      = row_ptr + (N_CNT + 1);             // NB2
    int*   bucket_ptr = bhist + NB2;                       // NB2+1
    int*   bcur       = bucket_ptr + (NB2 + 1);            // NB2
    float* dinv       = (float*)(bcur + NB2);              // N
    unsigned int* staging = (unsigned int*)(dinv + N_CNT); // nnz
    unsigned int* col_s   = staging + nnz;                 // nnz

    const int tpb = 256;

    // ---- CSR build: bucket totals (LDS hist), tiny scan, partition, place ----
    hipMemsetAsync(bhist, 0, NB2 * sizeof(int), stream);
    bucket_hist<<<512, tpb, 0, stream>>>(rows, bhist, nnz);
    bucket_scan<<<1, 64, 0, stream>>>(bhist, bucket_ptr, bcur);
    partition_kernel<<<(nnz + CH - 1) / CH, tpb, 0, stream>>>(
        rows, cols, bcur, staging, nnz);
    binplace_kernel<<<NB2, BROWS, 0, stream>>>(
        bucket_ptr, staging, col_s, row_ptr, dinv);

    // ---- dinv-scaled initial embeddings ----
    init_kernel<<<(N_CNT * 8 + tpb - 1) / tpb, tpb, 0, stream>>>(
        (const float4*)ue, (const float4*)ie, dinv, hs0, (float4*)acc);

    // ---- 3 propagation layers, split user/item for L2 locality ----
    uint4* cur = hs0;
    uint4* nxt = hs1;
    const int ublocks = (U_CNT + 31) / 32;
    const int iblocks = (N_CNT - U_CNT + 31) / 32;
    for (int l = 0; l < 3; ++l) {
        int last = (l == 2) ? 1 : 0;
        spmm_gather<<<ublocks, tpb, 0, stream>>>(
            row_ptr, col_s, dinv, cur, nxt, (float4*)acc, 0, U_CNT, last);
        spmm_gather<<<iblocks, tpb, 0, stream>>>(
            row_ptr, col_s, dinv, cur, nxt, (float4*)acc, U_CNT, N_CNT, last);
        uint4* tmp = cur; cur = nxt; nxt = tmp;
    }
}